// Round 10
// baseline (90.303 us; speedup 1.0000x reference)
//
#include <hip/hip_runtime.h>
#include <hip/hip_bf16.h>

typedef __attribute__((ext_vector_type(8))) short short8;
typedef __attribute__((ext_vector_type(4))) float f32x4;

#define B_SZ 64
#define T_SZ 8192
#define D_SZ 128
#define U_SZ 128
#define T_TILE 128
#define N_TILES (T_SZ / T_TILE)   /* 64 tiles per batch */
#define GRID_P (B_SZ * N_TILES)   /* 4096 blocks, 1 tile each */
#define P_STRIDE 132              /* c[128] + m + s, padded */
#define WT_LD 136                 /* bf16 row stride: 272B -> 4-bank stagger */

__device__ __forceinline__ unsigned short f2bf(float f) {
  unsigned int u = __builtin_bit_cast(unsigned int, f);
  u += 0x7fffu + ((u >> 16) & 1u);
  return (unsigned short)(u >> 16);
}

__device__ __forceinline__ float bf2f(unsigned short s) {
  return __builtin_bit_cast(float, (unsigned int)s << 16);
}

__device__ __forceinline__ float fast_tanh(float x) {
  float e = __expf(2.0f * x);
  return 1.0f - 2.0f * __builtin_amdgcn_rcpf(e + 1.0f);
}

// DPP row-reduce within each 16-lane row (VALU pipe only).
template<int CTRL>
__device__ __forceinline__ float dpp_add(float v) {
  int t = __builtin_amdgcn_update_dpp(0, __builtin_bit_cast(int, v),
                                      CTRL, 0xf, 0xf, true);
  return v + __builtin_bit_cast(float, t);
}
__device__ __forceinline__ float row_reduce16(float v) {
  v = dpp_add<0x118>(v);  // row_shr:8
  v = dpp_add<0x114>(v);  // row_shr:4
  v = dpp_add<0x112>(v);  // row_shr:2
  v = dpp_add<0x111>(v);  // row_shr:1
  return v;               // lane lr==15 of each 16-lane row holds the sum
}

__device__ __forceinline__ void cvt_tile(const float4 pf[8], short8 afrag[4]) {
#pragma unroll
  for (int kt = 0; kt < 4; ++kt) {
    short8 a;
#pragma unroll
    for (int j = 0; j < 4; ++j) {
      float4 f = pf[kt * 2 + (j >> 1)];
      a[j * 2]     = (short)f2bf(j & 1 ? f.z : f.x);
      a[j * 2 + 1] = (short)f2bf(j & 1 ? f.w : f.y);
    }
    afrag[kt] = a;
  }
}

// ---------------------------------------------------------------------------
// Kernel 0: W [d][u] fp32 -> Wt [u][d] bf16 in workspace (once, tiny)
// ---------------------------------------------------------------------------
__global__ void k_prep(const float* __restrict__ wk, unsigned short* __restrict__ wt) {
  int i = blockIdx.x * 256 + threadIdx.x;
  if (i < D_SZ * U_SZ) {
    int d = i >> 7, u = i & 127;
    wt[u * D_SZ + d] = f2bf(wk[i]);
  }
}

// ---------------------------------------------------------------------------
// Kernel 1: R0's dispatch regime (4096 one-shot blocks; the only structure
// measured at 6.8 TB/s on this pattern) + single-x-read register context.
// Block-level overlap does the latency hiding: 16 blocks queued per CU; a
// finishing block's successor issues its 64-KB load burst while the other
// resident blocks compute. x loads are issued FIRST in the prologue (before
// Wt staging, pinned by sched_barrier) so HBM service starts immediately.
// Per-wave softmax over the wave's 32 rows; one cross-wave merge at the end.
// No launch_bounds cap (R4 spill lesson); peak live regs ~90.
// ---------------------------------------------------------------------------
__global__ __launch_bounds__(256) void k_partial(
    const float* __restrict__ x, const unsigned short* __restrict__ wt_g,
    const float* __restrict__ wb, const float* __restrict__ v,
    const float* __restrict__ vb, float* __restrict__ pbuf)
{
  __shared__ unsigned short wt[U_SZ][WT_LD];  // 34816 B
  __shared__ float wb_s[U_SZ], v_s[U_SZ];     // 1 KB
  __shared__ float logits[4][32];             // wave-private slices
  __shared__ float fin[4][D_SZ];              // per-wave context partials
  __shared__ float fm[4], fs[4];

  const int tid  = threadIdx.x;
  const int bidx = blockIdx.x;
  const int b    = bidx >> 6;       // /N_TILES
  const int tile = bidx & 63;

  const int w  = tid >> 6;          // wave 0..3 -> rows w*32..w*32+31
  const int l  = tid & 63;
  const int lr = l & 15;            // A row within each 16-row subtile
  const int lh = l >> 4;            // k-subchunk / D-col group

  // ---- issue the block's x loads first: HBM latency starts now ----
  const float* xr0 = x + ((size_t)b * T_SZ + tile * T_TILE + w * 32 + lr) * D_SZ + lh * 8;
  const float* xr1 = xr0 + 16 * D_SZ;
  float4 pf0[8], pf1[8];
#pragma unroll
  for (int kt = 0; kt < 4; ++kt) {
    pf0[kt * 2]     = *(const float4*)(xr0 + kt * 32);
    pf0[kt * 2 + 1] = *(const float4*)(xr0 + kt * 32 + 4);
    pf1[kt * 2]     = *(const float4*)(xr1 + kt * 32);
    pf1[kt * 2 + 1] = *(const float4*)(xr1 + kt * 32 + 4);
  }
  __builtin_amdgcn_sched_barrier(0);   // x loads may not sink below this

  // ---- stage Wt (32 KB, L2-hot after first blocks) into padded LDS ----
  for (int i = tid; i < U_SZ * 16; i += 256) {
    int row = i >> 4, c16 = i & 15;
    uint4 val = ((const uint4*)wt_g)[i];
    *(uint4*)&wt[row][c16 * 8] = val;
  }
  if (tid < U_SZ) { wb_s[tid] = wb[tid]; v_s[tid] = v[tid]; }
  __syncthreads();

  short8 a0[4], a1[4];
  cvt_tile(pf0, a0);
  cvt_tile(pf1, a1);

  // ---- logits: 8 u-tiles x 4 k-tiles MFMA x 2 row-subtiles ----
  float lg0[4] = {0.f, 0.f, 0.f, 0.f};
  float lg1[4] = {0.f, 0.f, 0.f, 0.f};
#pragma unroll
  for (int ut = 0; ut < 8; ++ut) {
    f32x4 acc0 = {0.f, 0.f, 0.f, 0.f};
    f32x4 acc1 = {0.f, 0.f, 0.f, 0.f};
#pragma unroll
    for (int kt = 0; kt < 4; ++kt) {
      short8 bfrag = *(const short8*)&wt[ut * 16 + lr][kt * 32 + lh * 8];
      acc0 = __builtin_amdgcn_mfma_f32_16x16x32_bf16(a0[kt], bfrag, acc0, 0, 0, 0);
      acc1 = __builtin_amdgcn_mfma_f32_16x16x32_bf16(a1[kt], bfrag, acc1, 0, 0, 0);
    }
    const float wbv = wb_s[ut * 16 + lr];
    const float vv  = v_s[ut * 16 + lr];
#pragma unroll
    for (int r = 0; r < 4; ++r) {
      lg0[r] += fast_tanh(acc0[r] + wbv) * vv;
      lg1[r] += fast_tanh(acc1[r] + wbv) * vv;
    }
  }

  // reduce over the 16 u-columns via DPP; store at lr==15 lanes
#pragma unroll
  for (int r = 0; r < 4; ++r) {
    lg0[r] = row_reduce16(lg0[r]);
    lg1[r] = row_reduce16(lg1[r]);
  }
  const float vbias = vb[0];
  if (lr == 15) {
#pragma unroll
    for (int r = 0; r < 4; ++r) {
      logits[w][lh * 4 + r]      = lg0[r] + vbias;
      logits[w][16 + lh * 4 + r] = lg1[r] + vbias;
    }
  }

  // ---- per-wave softmax over the wave's 32 rows (wave-private LDS) ----
  float lv0 = logits[w][lr];        // same-wave LDS RAW: lgkmcnt only
  float lv1 = logits[w][16 + lr];
  float mx = fmaxf(lv0, lv1);
#pragma unroll
  for (int k = 1; k <= 8; k <<= 1) mx = fmaxf(mx, __shfl_xor(mx, k, 64));
  const float pr0 = __expf(lv0 - mx);
  const float pr1 = __expf(lv1 - mx);
  float ss = pr0 + pr1;
#pragma unroll
  for (int k = 1; k <= 8; k <<= 1) ss += __shfl_xor(ss, k, 64);

  // ---- context from registers: cv = pr0*x0 + pr1*x1, DPP reduce 16 rows ----
#pragma unroll
  for (int kt = 0; kt < 4; ++kt) {
    float cs[8];
#pragma unroll
    for (int j = 0; j < 8; ++j) {
      float cv = fmaf(pr1, bf2f((unsigned short)a1[kt][j]),
                      pr0 * bf2f((unsigned short)a0[kt][j]));
      cs[j] = row_reduce16(cv);
    }
    if (lr == 15) {
      f32x4 v0 = {cs[0], cs[1], cs[2], cs[3]};
      f32x4 v1 = {cs[4], cs[5], cs[6], cs[7]};
      *(f32x4*)&fin[w][kt * 32 + lh * 8]     = v0;
      *(f32x4*)&fin[w][kt * 32 + lh * 8 + 4] = v1;
    }
  }
  if (l == 0) { fm[w] = mx; fs[w] = ss; }
  __syncthreads();

  // ---- cross-wave merge + write partial record ----
  const float m_blk = fmaxf(fmaxf(fm[0], fm[1]), fmaxf(fm[2], fm[3]));
  const float e0 = __expf(fm[0] - m_blk);
  const float e1 = __expf(fm[1] - m_blk);
  const float e2 = __expf(fm[2] - m_blk);
  const float e3 = __expf(fm[3] - m_blk);
  float* pb = pbuf + (size_t)bidx * P_STRIDE;
  if (tid < 128) {
    pb[tid] = fin[0][tid] * e0 + fin[1][tid] * e1
            + fin[2][tid] * e2 + fin[3][tid] * e3;
  } else if (tid == 128) {
    pb[128] = m_blk;
  } else if (tid == 129) {
    pb[129] = fs[0] * e0 + fs[1] * e1 + fs[2] * e2 + fs[3] * e3;
  }
}

// ---------------------------------------------------------------------------
// Kernel 2: combine 64 tile-partials per batch with global softmax rescale
// ---------------------------------------------------------------------------
__global__ __launch_bounds__(128) void k_combine(const float* __restrict__ pbuf,
                                                 float* __restrict__ out)
{
  const int b = blockIdx.x, tid = threadIdx.x;
  __shared__ float sc[N_TILES];
  __shared__ float stot_s;
  const float* pb = pbuf + (size_t)b * N_TILES * P_STRIDE;

  if (tid < 64) {
    float m = pb[tid * P_STRIDE + 128];
    float mx = m;
#pragma unroll
    for (int k = 1; k <= 32; k <<= 1) mx = fmaxf(mx, __shfl_xor(mx, k, 64));
    float e = __expf(m - mx);
    float s = pb[tid * P_STRIDE + 129] * e;
    float st = s;
#pragma unroll
    for (int k = 1; k <= 32; k <<= 1) st += __shfl_xor(st, k, 64);
    sc[tid] = e;
    if (tid == 0) stot_s = st;
  }
  __syncthreads();

  float c = 0.0f;
#pragma unroll 8
  for (int i = 0; i < N_TILES; ++i) c = fmaf(pb[(size_t)i * P_STRIDE + tid], sc[i], c);
  out[b * D_SZ + tid] = c / stot_s;
}

// ---------------------------------------------------------------------------
extern "C" void kernel_launch(void* const* d_in, const int* in_sizes, int n_in,
                              void* d_out, int out_size, void* d_ws, size_t ws_size,
                              hipStream_t stream) {
  const float* x  = (const float*)d_in[0];  // [B,T,D]
  const float* wk = (const float*)d_in[1];  // [D,U]
  const float* wb = (const float*)d_in[2];  // [U]
  const float* vk = (const float*)d_in[3];  // [U,1]
  const float* vb = (const float*)d_in[4];  // [1]
  float* out = (float*)d_out;               // [B,D]

  unsigned short* wt = (unsigned short*)d_ws;       // 32 KB bf16 Wt[u][d]
  float* pbuf = (float*)((char*)d_ws + 32768);      // 4096 * 132 floats

  k_prep<<<64, 256, 0, stream>>>(wk, wt);
  k_partial<<<GRID_P, 256, 0, stream>>>(x, wt, wb, vk, vb, pbuf);
  k_combine<<<B_SZ, 128, 0, stream>>>(pbuf, out);
}

// Round 11
// 75.304 us; speedup vs baseline: 1.1992x; 1.1992x over previous
//
#include <hip/hip_runtime.h>
#include <hip/hip_bf16.h>

typedef __attribute__((ext_vector_type(8))) short short8;
typedef __attribute__((ext_vector_type(4))) float f32x4;

#define B_SZ 64
#define T_SZ 8192
#define D_SZ 128
#define U_SZ 128
#define T_TILE 64
#define GRID_P 2048
#define TILES_PER_BLK 4           /* 2048 blocks x 4 tiles x 64 rows = 64*8192 */
#define BLKS_PER_B 32             /* GRID_P / B_SZ */
#define P_STRIDE 132              /* c[128] + m + s, padded */
#define WT_LD 136                 /* bf16 row stride: 272B */

__device__ __forceinline__ unsigned short f2bf(float f) {
  unsigned int u = __builtin_bit_cast(unsigned int, f);
  u += 0x7fffu + ((u >> 16) & 1u);
  return (unsigned short)(u >> 16);
}

__device__ __forceinline__ float bf2f(unsigned short s) {
  return __builtin_bit_cast(float, (unsigned int)s << 16);
}

__device__ __forceinline__ float fast_tanh(float x) {
  float e = __expf(2.0f * x);
  return 1.0f - 2.0f * __builtin_amdgcn_rcpf(e + 1.0f);
}

// DPP row-reduce within each 16-lane row (VALU pipe only).
template<int CTRL>
__device__ __forceinline__ float dpp_add(float v) {
  int t = __builtin_amdgcn_update_dpp(0, __builtin_bit_cast(int, v),
                                      CTRL, 0xf, 0xf, true);
  return v + __builtin_bit_cast(float, t);
}
__device__ __forceinline__ float row_reduce16(float v) {
  v = dpp_add<0x118>(v);  // row_shr:8
  v = dpp_add<0x114>(v);  // row_shr:4
  v = dpp_add<0x112>(v);  // row_shr:2
  v = dpp_add<0x111>(v);  // row_shr:1
  return v;               // lane lr==15 of each 16-lane row holds the sum
}

__device__ __forceinline__ void cvt_tile(const f32x4 pf[8], short8 afrag[4]) {
#pragma unroll
  for (int kt = 0; kt < 4; ++kt) {
    short8 a;
#pragma unroll
    for (int j = 0; j < 4; ++j) {
      f32x4 f = pf[kt * 2 + (j >> 1)];
      a[j * 2]     = (short)f2bf(j & 1 ? f[2] : f[0]);
      a[j * 2 + 1] = (short)f2bf(j & 1 ? f[3] : f[1]);
    }
    afrag[kt] = a;
  }
}

// ---------------------------------------------------------------------------
// Kernel 0: W [d][u] fp32 -> Wt [u][d] bf16 in workspace (once, tiny)
// ---------------------------------------------------------------------------
__global__ void k_prep(const float* __restrict__ wk, unsigned short* __restrict__ wt) {
  int i = blockIdx.x * 256 + threadIdx.x;
  if (i < D_SZ * U_SZ) {
    int d = i >> 7, u = i & 127;
    wt[u * D_SZ + d] = f2bf(wk[i]);
  }
}

// ---------------------------------------------------------------------------
// Kernel 1: R8 structure (best: 63.9 us) + stream-efficiency changes:
//  - nontemporal x loads (x is read once, never reused -> no L2 allocate)
//  - TPB=4 / 2048 blocks: more resident-block diversity per CU, shorter tail
//  - prologue reorder: tile-0 x loads issue BEFORE Wt staging (pinned by
//    sched_barrier; only 32 VGPRs live) so HBM service starts immediately
// Per-wave online softmax; sched_barrier-only fences in the loop (no block
// sync); per-lane context accumulate; one merge after the loop.
// ---------------------------------------------------------------------------
__global__ __launch_bounds__(256) void k_partial(
    const float* __restrict__ x, const unsigned short* __restrict__ wt_g,
    const float* __restrict__ wb, const float* __restrict__ v,
    const float* __restrict__ vb, float* __restrict__ pbuf)
{
  __shared__ unsigned short wt[U_SZ][WT_LD];  // 34816 B
  __shared__ float wb_s[U_SZ], v_s[U_SZ];     // 1 KB
  __shared__ float logits[4][16];             // wave-private slices
  __shared__ float fin[4][D_SZ];              // final merge buffers
  __shared__ float fm[4], fs[4];

  const int tid  = threadIdx.x;
  const int bidx = blockIdx.x;

  const int w  = tid >> 6;          // wave 0..3 -> rows w*16..w*16+15 of tile
  const int l  = tid & 63;
  const int lr = l & 15;            // A row within the wave's 16-row subtile
  const int lh = l >> 4;            // k-subchunk / D-col group

  const int b        = bidx >> 5;                      // /BLKS_PER_B
  const int row0     = (bidx & (BLKS_PER_B - 1)) * (TILES_PER_BLK * T_TILE);
  const float* xbase = x + ((size_t)b * T_SZ + row0 + w * 16 + lr) * D_SZ + lh * 8;

  // ---- tile-0 x loads first: HBM service starts at block launch ----
  f32x4 pf[8];
#pragma unroll
  for (int kt = 0; kt < 4; ++kt) {
    pf[kt * 2]     = __builtin_nontemporal_load((const f32x4*)(xbase + kt * 32));
    pf[kt * 2 + 1] = __builtin_nontemporal_load((const f32x4*)(xbase + kt * 32 + 4));
  }
  __builtin_amdgcn_sched_barrier(0);   // x loads may not sink below this

  for (int i = tid; i < U_SZ * 16; i += 256) {
    int row = i >> 4, c16 = i & 15;
    uint4 val = ((const uint4*)wt_g)[i];
    *(uint4*)&wt[row][c16 * 8] = val;
  }
  if (tid < U_SZ) { wb_s[tid] = wb[tid]; v_s[tid] = v[tid]; }
  __syncthreads();

  const float vbias = vb[0];
  short8 afrag[4];
  cvt_tile(pf, afrag);

  float m_run = -3.0e38f, s_run = 0.0f;
  float rc[4][8];
#pragma unroll
  for (int kt = 0; kt < 4; ++kt)
#pragma unroll
    for (int j = 0; j < 8; ++j) rc[kt][j] = 0.0f;

  for (int it = 0; it < TILES_PER_BLK; ++it) {
    // issue next tile's loads; pinned at the top by sched_barrier below
    if (it + 1 < TILES_PER_BLK) {
      const float* p = xbase + (size_t)(it + 1) * T_TILE * D_SZ;
#pragma unroll
      for (int kt = 0; kt < 4; ++kt) {
        pf[kt * 2]     = __builtin_nontemporal_load((const f32x4*)(p + kt * 32));
        pf[kt * 2 + 1] = __builtin_nontemporal_load((const f32x4*)(p + kt * 32 + 4));
      }
      __builtin_amdgcn_sched_barrier(0);  // loads may not sink below this
    }

    // ---- logits: 8 u-tiles x 4 k-tiles MFMA + tanh + v-weighted u-sum ----
    float lg[4] = {0.f, 0.f, 0.f, 0.f};
#pragma unroll
    for (int ut = 0; ut < 8; ++ut) {
      f32x4 acc = {0.f, 0.f, 0.f, 0.f};
#pragma unroll
      for (int kt = 0; kt < 4; ++kt) {
        short8 bfrag = *(const short8*)&wt[ut * 16 + lr][kt * 32 + lh * 8];
        acc = __builtin_amdgcn_mfma_f32_16x16x32_bf16(afrag[kt], bfrag, acc, 0, 0, 0);
      }
      const float wbv = wb_s[ut * 16 + lr];
      const float vv  = v_s[ut * 16 + lr];
#pragma unroll
      for (int r = 0; r < 4; ++r)
        lg[r] += fast_tanh(acc[r] + wbv) * vv;
    }
#pragma unroll
    for (int r = 0; r < 4; ++r) lg[r] = row_reduce16(lg[r]);
    if (lr == 15) {
#pragma unroll
      for (int r = 0; r < 4; ++r)
        logits[w][lh * 4 + r] = lg[r] + vbias;   // wave-private: no barrier
    }

    // ---- per-wave online softmax over this tile's 16 rows ----
    float lv = logits[w][lr];         // same-wave LDS RAW: lgkmcnt only
    float mx = lv;
#pragma unroll
    for (int k = 1; k <= 8; k <<= 1) mx = fmaxf(mx, __shfl_xor(mx, k, 64));
    const float m_new = fmaxf(m_run, mx);
    const float e_old = __expf(m_run - m_new);
    const float pr    = __expf(lv - m_new);     // own row's weight
    float ss = pr;
#pragma unroll
    for (int k = 1; k <= 8; k <<= 1) ss += __shfl_xor(ss, k, 64);
    s_run = s_run * e_old + ss;
    m_run = m_new;

    // ---- per-lane context accumulate (no per-tile reduce) ----
#pragma unroll
    for (int kt = 0; kt < 4; ++kt) {
#pragma unroll
      for (int j = 0; j < 8; ++j) {
        rc[kt][j] = fmaf(rc[kt][j], e_old,
                         pr * bf2f((unsigned short)afrag[kt][j]));
      }
    }

    // ---- scheduling fence only (no block sync): cvt may not hoist up ----
    __builtin_amdgcn_sched_barrier(0);
    if (it + 1 < TILES_PER_BLK) cvt_tile(pf, afrag);
  }

  // ---- one-time 16-row reduce + cross-wave merge ----
  if (l == 0) { fm[w] = m_run; fs[w] = s_run; }
  __syncthreads();
  const float m_blk = fmaxf(fmaxf(fm[0], fm[1]), fmaxf(fm[2], fm[3]));
  const float e_w   = __expf(m_run - m_blk);
#pragma unroll
  for (int kt = 0; kt < 4; ++kt) {
    float cs[8];
#pragma unroll
    for (int j = 0; j < 8; ++j) cs[j] = row_reduce16(rc[kt][j]);
    if (lr == 15) {
      f32x4 v0 = {cs[0] * e_w, cs[1] * e_w, cs[2] * e_w, cs[3] * e_w};
      f32x4 v1 = {cs[4] * e_w, cs[5] * e_w, cs[6] * e_w, cs[7] * e_w};
      *(f32x4*)&fin[w][kt * 32 + lh * 8]     = v0;
      *(f32x4*)&fin[w][kt * 32 + lh * 8 + 4] = v1;
    }
  }
  __syncthreads();

  float* pb = pbuf + (size_t)bidx * P_STRIDE;
  if (tid < 128) {
    pb[tid] = fin[0][tid] + fin[1][tid] + fin[2][tid] + fin[3][tid];
  } else if (tid == 128) {
    pb[128] = m_blk;
  } else if (tid == 129) {
    float sb = fs[0] * __expf(fm[0] - m_blk) + fs[1] * __expf(fm[1] - m_blk)
             + fs[2] * __expf(fm[2] - m_blk) + fs[3] * __expf(fm[3] - m_blk);
    pb[129] = sb;
  }
}

// ---------------------------------------------------------------------------
// Kernel 2: combine 32 block-partials per batch with global softmax rescale
// ---------------------------------------------------------------------------
__global__ __launch_bounds__(128) void k_combine(const float* __restrict__ pbuf,
                                                 float* __restrict__ out)
{
  const int b = blockIdx.x, tid = threadIdx.x;
  __shared__ float sm[BLKS_PER_B], sden[BLKS_PER_B];
  const float* base = pbuf + (size_t)b * BLKS_PER_B * P_STRIDE;

  if (tid < BLKS_PER_B) {
    sm[tid]   = base[tid * P_STRIDE + 128];
    sden[tid] = base[tid * P_STRIDE + 129];
  }
  __syncthreads();

  float mx = -3.0e38f;
#pragma unroll
  for (int i = 0; i < BLKS_PER_B; ++i) mx = fmaxf(mx, sm[i]);
  float den = 0.0f, c = 0.0f;
#pragma unroll 8
  for (int i = 0; i < BLKS_PER_B; ++i) {
    float e = __expf(sm[i] - mx);
    den += sden[i] * e;
    c = fmaf(base[(size_t)i * P_STRIDE + tid], e, c);
  }
  out[b * D_SZ + tid] = c / den;
}

// ---------------------------------------------------------------------------
extern "C" void kernel_launch(void* const* d_in, const int* in_sizes, int n_in,
                              void* d_out, int out_size, void* d_ws, size_t ws_size,
                              hipStream_t stream) {
  const float* x  = (const float*)d_in[0];  // [B,T,D]
  const float* wk = (const float*)d_in[1];  // [D,U]
  const float* wb = (const float*)d_in[2];  // [U]
  const float* vk = (const float*)d_in[3];  // [U,1]
  const float* vb = (const float*)d_in[4];  // [1]
  float* out = (float*)d_out;               // [B,D]

  unsigned short* wt = (unsigned short*)d_ws;       // 32 KB bf16 Wt[u][d]
  float* pbuf = (float*)((char*)d_ws + 32768);      // 2048 * 132 floats

  k_prep<<<64, 256, 0, stream>>>(wk, wt);
  k_partial<<<GRID_P, 256, 0, stream>>>(x, wt, wb, vk, vb, pbuf);
  k_combine<<<B_SZ, 128, 0, stream>>>(pbuf, out);
}

// Round 12
// 61.558 us; speedup vs baseline: 1.4670x; 1.2233x over previous
//
#include <hip/hip_runtime.h>
#include <hip/hip_bf16.h>

typedef __attribute__((ext_vector_type(8))) short short8;
typedef __attribute__((ext_vector_type(4))) float f32x4;
typedef __attribute__((ext_vector_type(4))) int int4v;

#define B_SZ 64
#define T_SZ 8192
#define D_SZ 128
#define U_SZ 128
#define T_TILE 64
#define GRID_P 1024
#define TILES_PER_BLK 8           /* 1024 blocks x 8 tiles x 64 rows = 64*8192 */
#define P_STRIDE 132              /* c[128] + m + s, padded */
#define WT_LD 136                 /* bf16 row stride: 272B */
#define TANH_SCALE 2.8853900817779268f   /* 2*log2(e): folds tanh's 2x and exp's log2e */

__device__ __forceinline__ unsigned short f2bf(float f) {
  unsigned int u = __builtin_bit_cast(unsigned int, f);
  u += 0x7fffu + ((u >> 16) & 1u);
  return (unsigned short)(u >> 16);
}

__device__ __forceinline__ float bf2f(unsigned short s) {
  return __builtin_bit_cast(float, (unsigned int)s << 16);
}

// tanh with the 2*log2e prefold: xs = 2*log2e*(Wx+b), tanh = 1 - 2/(2^xs + 1)
__device__ __forceinline__ float tanh_pre(float xs) {
  float e;
  asm("v_exp_f32 %0, %1" : "=v"(e) : "v"(xs));   // 2^xs; saturates to +-1 correctly
  return 1.0f - 2.0f * __builtin_amdgcn_rcpf(e + 1.0f);
}

// DPP row-reduce within each 16-lane row (VALU pipe only).
template<int CTRL>
__device__ __forceinline__ float dpp_add(float v) {
  int t = __builtin_amdgcn_update_dpp(0, __builtin_bit_cast(int, v),
                                      CTRL, 0xf, 0xf, true);
  return v + __builtin_bit_cast(float, t);
}
__device__ __forceinline__ float row_reduce16(float v) {
  v = dpp_add<0x118>(v);  // row_shr:8
  v = dpp_add<0x114>(v);  // row_shr:4
  v = dpp_add<0x112>(v);  // row_shr:2
  v = dpp_add<0x111>(v);  // row_shr:1
  return v;               // lane lr==15 of each 16-lane row holds the sum
}

// fp32x8 -> bf16x8 via hardware packed converts (RNE), 4 insts + pack
__device__ __forceinline__ void cvt_tile(const f32x4 pf[8], short8 afrag[4]) {
#pragma unroll
  for (int kt = 0; kt < 4; ++kt) {
    f32x4 f0 = pf[kt * 2], f1 = pf[kt * 2 + 1];
    int w0, w1, w2, w3;
    asm("v_cvt_pk_bf16_f32 %0, %1, %2" : "=v"(w0) : "v"(f0[0]), "v"(f0[1]));
    asm("v_cvt_pk_bf16_f32 %0, %1, %2" : "=v"(w1) : "v"(f0[2]), "v"(f0[3]));
    asm("v_cvt_pk_bf16_f32 %0, %1, %2" : "=v"(w2) : "v"(f1[0]), "v"(f1[1]));
    asm("v_cvt_pk_bf16_f32 %0, %1, %2" : "=v"(w3) : "v"(f1[2]), "v"(f1[3]));
    int4v w = {w0, w1, w2, w3};
    afrag[kt] = __builtin_bit_cast(short8, w);
  }
}

// ---------------------------------------------------------------------------
// Kernel 0: W [d][u] fp32 -> Wt [u][d] bf16 PRESCALED by 2*log2e (once, tiny)
// ---------------------------------------------------------------------------
__global__ void k_prep(const float* __restrict__ wk, unsigned short* __restrict__ wt) {
  int i = blockIdx.x * 256 + threadIdx.x;
  if (i < D_SZ * U_SZ) {
    int d = i >> 7, u = i & 127;
    wt[u * D_SZ + d] = f2bf(wk[i] * TANH_SCALE);
  }
}

// ---------------------------------------------------------------------------
// Kernel 1: R8 shell exactly (best: 63.9us) + VALU cuts. R10's bundle
// (nontemporal/TPB4/reorder) regressed and is reverted. VALU was the
// bottleneck (issue-cyc/SIMD/tile ~4600 > HBM fair-share 3250):
//  - cvt_tile now uses v_cvt_pk_bf16_f32 (hw RNE): ~96 -> ~20 VALU
//  - tanh prefold (Wt,wb scaled by 2*log2e at prep): 128 -> 64 VALU
// ---------------------------------------------------------------------------
__global__ __launch_bounds__(256) void k_partial(
    const float* __restrict__ x, const unsigned short* __restrict__ wt_g,
    const float* __restrict__ wb, const float* __restrict__ v,
    const float* __restrict__ vb, float* __restrict__ pbuf)
{
  __shared__ unsigned short wt[U_SZ][WT_LD];  // 34816 B
  __shared__ float wb_s[U_SZ], v_s[U_SZ];     // 1 KB
  __shared__ float logits[4][16];             // wave-private slices
  __shared__ float fin[4][D_SZ];              // final merge buffers
  __shared__ float fm[4], fs[4];

  const int tid  = threadIdx.x;
  const int bidx = blockIdx.x;

  for (int i = tid; i < U_SZ * 16; i += 256) {
    int row = i >> 4, c16 = i & 15;
    uint4 val = ((const uint4*)wt_g)[i];
    *(uint4*)&wt[row][c16 * 8] = val;
  }
  if (tid < U_SZ) { wb_s[tid] = wb[tid] * TANH_SCALE; v_s[tid] = v[tid]; }
  __syncthreads();

  const int w  = tid >> 6;          // wave 0..3 -> rows w*16..w*16+15 of tile
  const int l  = tid & 63;
  const int lr = l & 15;            // A row within the wave's 16-row subtile
  const int lh = l >> 4;            // k-subchunk / D-col group
  const float vbias = vb[0];

  const int b        = bidx >> 4;
  const int row0     = (bidx & 15) * (TILES_PER_BLK * T_TILE);
  const float* xbase = x + ((size_t)b * T_SZ + row0 + w * 16 + lr) * D_SZ + lh * 8;

  f32x4 pf[8];
#pragma unroll
  for (int kt = 0; kt < 4; ++kt) {
    pf[kt * 2]     = *(const f32x4*)(xbase + kt * 32);
    pf[kt * 2 + 1] = *(const f32x4*)(xbase + kt * 32 + 4);
  }
  short8 afrag[4];
  cvt_tile(pf, afrag);

  float m_run = -3.0e38f, s_run = 0.0f;
  float rc[4][8];
#pragma unroll
  for (int kt = 0; kt < 4; ++kt)
#pragma unroll
    for (int j = 0; j < 8; ++j) rc[kt][j] = 0.0f;

  for (int it = 0; it < TILES_PER_BLK; ++it) {
    // issue next tile's loads; pinned at the top by sched_barrier below
    if (it + 1 < TILES_PER_BLK) {
      const float* p = xbase + (size_t)(it + 1) * T_TILE * D_SZ;
#pragma unroll
      for (int kt = 0; kt < 4; ++kt) {
        pf[kt * 2]     = *(const f32x4*)(p + kt * 32);
        pf[kt * 2 + 1] = *(const f32x4*)(p + kt * 32 + 4);
      }
      __builtin_amdgcn_sched_barrier(0);  // loads may not sink below this
    }

    // ---- logits: 8 u-tiles x 4 k-tiles MFMA + tanh + v-weighted u-sum ----
    float lg[4] = {0.f, 0.f, 0.f, 0.f};
#pragma unroll
    for (int ut = 0; ut < 8; ++ut) {
      f32x4 acc = {0.f, 0.f, 0.f, 0.f};
#pragma unroll
      for (int kt = 0; kt < 4; ++kt) {
        short8 bfrag = *(const short8*)&wt[ut * 16 + lr][kt * 32 + lh * 8];
        acc = __builtin_amdgcn_mfma_f32_16x16x32_bf16(afrag[kt], bfrag, acc, 0, 0, 0);
      }
      const float wbv = wb_s[ut * 16 + lr];
      const float vv  = v_s[ut * 16 + lr];
#pragma unroll
      for (int r = 0; r < 4; ++r)
        lg[r] += tanh_pre(acc[r] + wbv) * vv;
    }
#pragma unroll
    for (int r = 0; r < 4; ++r) lg[r] = row_reduce16(lg[r]);
    if (lr == 15) {
#pragma unroll
      for (int r = 0; r < 4; ++r)
        logits[w][lh * 4 + r] = lg[r] + vbias;   // wave-private: no barrier
    }

    // ---- per-wave online softmax over this tile's 16 rows ----
    float lv = logits[w][lr];         // same-wave LDS RAW: lgkmcnt only
    float mx = lv;
#pragma unroll
    for (int k = 1; k <= 8; k <<= 1) mx = fmaxf(mx, __shfl_xor(mx, k, 64));
    const float m_new = fmaxf(m_run, mx);
    const float e_old = __expf(m_run - m_new);
    const float pr    = __expf(lv - m_new);     // own row's weight
    float ss = pr;
#pragma unroll
    for (int k = 1; k <= 8; k <<= 1) ss += __shfl_xor(ss, k, 64);
    s_run = s_run * e_old + ss;
    m_run = m_new;

    // ---- per-lane context accumulate (no per-tile reduce) ----
#pragma unroll
    for (int kt = 0; kt < 4; ++kt) {
#pragma unroll
      for (int j = 0; j < 8; ++j) {
        rc[kt][j] = fmaf(rc[kt][j], e_old,
                         pr * bf2f((unsigned short)afrag[kt][j]));
      }
    }

    // ---- scheduling fence only (no block sync): cvt may not hoist up ----
    __builtin_amdgcn_sched_barrier(0);
    if (it + 1 < TILES_PER_BLK) cvt_tile(pf, afrag);
  }

  // ---- one-time 16-row reduce + cross-wave merge ----
  if (l == 0) { fm[w] = m_run; fs[w] = s_run; }
  __syncthreads();
  const float m_blk = fmaxf(fmaxf(fm[0], fm[1]), fmaxf(fm[2], fm[3]));
  const float e_w   = __expf(m_run - m_blk);
#pragma unroll
  for (int kt = 0; kt < 4; ++kt) {
    float cs[8];
#pragma unroll
    for (int j = 0; j < 8; ++j) cs[j] = row_reduce16(rc[kt][j]);
    if (lr == 15) {
      f32x4 v0 = {cs[0] * e_w, cs[1] * e_w, cs[2] * e_w, cs[3] * e_w};
      f32x4 v1 = {cs[4] * e_w, cs[5] * e_w, cs[6] * e_w, cs[7] * e_w};
      *(f32x4*)&fin[w][kt * 32 + lh * 8]     = v0;
      *(f32x4*)&fin[w][kt * 32 + lh * 8 + 4] = v1;
    }
  }
  __syncthreads();

  float* pb = pbuf + (size_t)bidx * P_STRIDE;
  if (tid < 128) {
    pb[tid] = fin[0][tid] + fin[1][tid] + fin[2][tid] + fin[3][tid];
  } else if (tid == 128) {
    pb[128] = m_blk;
  } else if (tid == 129) {
    float sb = fs[0] * __expf(fm[0] - m_blk) + fs[1] * __expf(fm[1] - m_blk)
             + fs[2] * __expf(fm[2] - m_blk) + fs[3] * __expf(fm[3] - m_blk);
    pb[129] = sb;
  }
}

// ---------------------------------------------------------------------------
// Kernel 2: combine 16 block-partials per batch with global softmax rescale
// ---------------------------------------------------------------------------
__global__ __launch_bounds__(128) void k_combine(const float* __restrict__ pbuf,
                                                 float* __restrict__ out)
{
  const int b = blockIdx.x, tid = threadIdx.x;
  __shared__ float sm[16], sden[16];
  const float* base = pbuf + (size_t)b * 16 * P_STRIDE;

  if (tid < 16) {
    sm[tid]   = base[tid * P_STRIDE + 128];
    sden[tid] = base[tid * P_STRIDE + 129];
  }
  __syncthreads();

  float mx = -3.0e38f;
#pragma unroll
  for (int i = 0; i < 16; ++i) mx = fmaxf(mx, sm[i]);
  float den = 0.0f, c = 0.0f;
#pragma unroll
  for (int i = 0; i < 16; ++i) {
    float e = __expf(sm[i] - mx);
    den += sden[i] * e;
    c = fmaf(base[(size_t)i * P_STRIDE + tid], e, c);
  }
  out[b * D_SZ + tid] = c / den;
}

// ---------------------------------------------------------------------------
extern "C" void kernel_launch(void* const* d_in, const int* in_sizes, int n_in,
                              void* d_out, int out_size, void* d_ws, size_t ws_size,
                              hipStream_t stream) {
  const float* x  = (const float*)d_in[0];  // [B,T,D]
  const float* wk = (const float*)d_in[1];  // [D,U]
  const float* wb = (const float*)d_in[2];  // [U]
  const float* vk = (const float*)d_in[3];  // [U,1]
  const float* vb = (const float*)d_in[4];  // [1]
  float* out = (float*)d_out;               // [B,D]

  unsigned short* wt = (unsigned short*)d_ws;       // 32 KB bf16 Wt[u][d] (prescaled)
  float* pbuf = (float*)((char*)d_ws + 32768);      // 1024 * 132 floats

  k_prep<<<64, 256, 0, stream>>>(wk, wt);
  k_partial<<<GRID_P, 256, 0, stream>>>(x, wt, wb, vk, vb, pbuf);
  k_combine<<<B_SZ, 128, 0, stream>>>(pbuf, out);
}

// Round 13
// 61.469 us; speedup vs baseline: 1.4691x; 1.0014x over previous
//
#include <hip/hip_runtime.h>
#include <hip/hip_bf16.h>

typedef __attribute__((ext_vector_type(8))) short short8;
typedef __attribute__((ext_vector_type(4))) float f32x4;
typedef __attribute__((ext_vector_type(4))) int int4v;

#define B_SZ 64
#define T_SZ 8192
#define D_SZ 128
#define U_SZ 128
#define T_TILE 64
#define GRID_P 1024
#define TILES_PER_BLK 8           /* 1024 blocks x 8 tiles x 64 rows = 64*8192 */
#define P_STRIDE 132              /* c[128] + m + s, padded */
#define WT_LD 136                 /* bf16 row stride: 272B */
#define TANH_SCALE 2.8853900817779268f   /* 2*log2(e): folds tanh's 2x and exp's log2e */
#define DEFER_THR 8.0f            /* defer-max rescale threshold (T13) */

__device__ __forceinline__ unsigned short f2bf(float f) {
  unsigned int u = __builtin_bit_cast(unsigned int, f);
  u += 0x7fffu + ((u >> 16) & 1u);
  return (unsigned short)(u >> 16);
}

__device__ __forceinline__ float bf2f(unsigned short s) {
  return __builtin_bit_cast(float, (unsigned int)s << 16);
}

__device__ __forceinline__ float exp2_fast(float xs) {
  float e;
  asm("v_exp_f32 %0, %1" : "=v"(e) : "v"(xs));   // 2^xs
  return e;
}

// DPP row-reduce within each 16-lane row (VALU pipe only).
template<int CTRL>
__device__ __forceinline__ float dpp_add(float v) {
  int t = __builtin_amdgcn_update_dpp(0, __builtin_bit_cast(int, v),
                                      CTRL, 0xf, 0xf, true);
  return v + __builtin_bit_cast(float, t);
}
__device__ __forceinline__ float row_reduce16(float v) {
  v = dpp_add<0x118>(v);  // row_shr:8
  v = dpp_add<0x114>(v);  // row_shr:4
  v = dpp_add<0x112>(v);  // row_shr:2
  v = dpp_add<0x111>(v);  // row_shr:1
  return v;               // lane lr==15 of each 16-lane row holds the sum
}

// fp32x8 -> bf16x8 via hardware packed converts (RNE)
__device__ __forceinline__ void cvt_tile(const f32x4 pf[8], short8 afrag[4]) {
#pragma unroll
  for (int kt = 0; kt < 4; ++kt) {
    f32x4 f0 = pf[kt * 2], f1 = pf[kt * 2 + 1];
    int w0, w1, w2, w3;
    asm("v_cvt_pk_bf16_f32 %0, %1, %2" : "=v"(w0) : "v"(f0[0]), "v"(f0[1]));
    asm("v_cvt_pk_bf16_f32 %0, %1, %2" : "=v"(w1) : "v"(f0[2]), "v"(f0[3]));
    asm("v_cvt_pk_bf16_f32 %0, %1, %2" : "=v"(w2) : "v"(f1[0]), "v"(f1[1]));
    asm("v_cvt_pk_bf16_f32 %0, %1, %2" : "=v"(w3) : "v"(f1[2]), "v"(f1[3]));
    int4v w = {w0, w1, w2, w3};
    afrag[kt] = __builtin_bit_cast(short8, w);
  }
}

// ---------------------------------------------------------------------------
// Kernel 0: W [d][u] fp32 -> Wt [u][d] bf16 PRESCALED by 2*log2e (once, tiny)
// ---------------------------------------------------------------------------
__global__ void k_prep(const float* __restrict__ wk, unsigned short* __restrict__ wt) {
  int i = blockIdx.x * 256 + threadIdx.x;
  if (i < D_SZ * U_SZ) {
    int d = i >> 7, u = i & 127;
    wt[u * D_SZ + d] = f2bf(wk[i] * TANH_SCALE);
  }
}

// ---------------------------------------------------------------------------
// Kernel 1: R11 shell + three algebraic VALU cuts:
//  1. bias in MFMA acc init (C/D col=lane&15 -> same wbv for all 4 regs)
//  2. sum(v*tanh) = vsum - 2*sum(v*rcp(e+1)); vsum loop-invariant
//  3. defer-max (T13): skip rc/s rescale while tile max grows < 8;
//     common-path rc accumulate = bf2f+fmac only
// ---------------------------------------------------------------------------
__global__ __launch_bounds__(256) void k_partial(
    const float* __restrict__ x, const unsigned short* __restrict__ wt_g,
    const float* __restrict__ wb, const float* __restrict__ v,
    const float* __restrict__ vb, float* __restrict__ pbuf)
{
  __shared__ unsigned short wt[U_SZ][WT_LD];  // 34816 B
  __shared__ float wb_s[U_SZ], v_s[U_SZ];     // 1 KB
  __shared__ float logits[4][16];             // wave-private slices
  __shared__ float fin[4][D_SZ];              // final merge buffers
  __shared__ float fm[4], fs[4];

  const int tid  = threadIdx.x;
  const int bidx = blockIdx.x;

  for (int i = tid; i < U_SZ * 16; i += 256) {
    int row = i >> 4, c16 = i & 15;
    uint4 val = ((const uint4*)wt_g)[i];
    *(uint4*)&wt[row][c16 * 8] = val;
  }
  if (tid < U_SZ) { wb_s[tid] = wb[tid] * TANH_SCALE; v_s[tid] = v[tid]; }
  __syncthreads();

  const int w  = tid >> 6;          // wave 0..3 -> rows w*16..w*16+15 of tile
  const int l  = tid & 63;
  const int lr = l & 15;            // A row within the wave's 16-row subtile
  const int lh = l >> 4;            // k-subchunk / D-col group
  const float vbias = vb[0];

  // loop-invariant: sum of v over this lane's u-column set
  float vsum = 0.0f;
#pragma unroll
  for (int ut = 0; ut < 8; ++ut) vsum += v_s[ut * 16 + lr];

  const int b        = bidx >> 4;
  const int row0     = (bidx & 15) * (TILES_PER_BLK * T_TILE);
  const float* xbase = x + ((size_t)b * T_SZ + row0 + w * 16 + lr) * D_SZ + lh * 8;

  f32x4 pf[8];
#pragma unroll
  for (int kt = 0; kt < 4; ++kt) {
    pf[kt * 2]     = *(const f32x4*)(xbase + kt * 32);
    pf[kt * 2 + 1] = *(const f32x4*)(xbase + kt * 32 + 4);
  }
  short8 afrag[4];
  cvt_tile(pf, afrag);

  float m_run = -3.0e38f, s_run = 0.0f;
  float rc[4][8];
#pragma unroll
  for (int kt = 0; kt < 4; ++kt)
#pragma unroll
    for (int j = 0; j < 8; ++j) rc[kt][j] = 0.0f;

  for (int it = 0; it < TILES_PER_BLK; ++it) {
    // issue next tile's loads; pinned at the top by sched_barrier below
    if (it + 1 < TILES_PER_BLK) {
      const float* p = xbase + (size_t)(it + 1) * T_TILE * D_SZ;
#pragma unroll
      for (int kt = 0; kt < 4; ++kt) {
        pf[kt * 2]     = *(const f32x4*)(p + kt * 32);
        pf[kt * 2 + 1] = *(const f32x4*)(p + kt * 32 + 4);
      }
      __builtin_amdgcn_sched_barrier(0);  // loads may not sink below this
    }

    // ---- logits: 8 u-tiles x 4 k-tiles MFMA; bias in acc init;
    //      lg accumulates sum(v*rcp(2^acc + 1)) ----
    float lg[4] = {0.f, 0.f, 0.f, 0.f};
#pragma unroll
    for (int ut = 0; ut < 8; ++ut) {
      const float wbv = wb_s[ut * 16 + lr];
      f32x4 acc = {wbv, wbv, wbv, wbv};
#pragma unroll
      for (int kt = 0; kt < 4; ++kt) {
        short8 bfrag = *(const short8*)&wt[ut * 16 + lr][kt * 32 + lh * 8];
        acc = __builtin_amdgcn_mfma_f32_16x16x32_bf16(afrag[kt], bfrag, acc, 0, 0, 0);
      }
      const float vv = v_s[ut * 16 + lr];
#pragma unroll
      for (int r = 0; r < 4; ++r)
        lg[r] = fmaf(vv, __builtin_amdgcn_rcpf(exp2_fast(acc[r]) + 1.0f), lg[r]);
    }
#pragma unroll
    for (int r = 0; r < 4; ++r) {
      lg[r] = row_reduce16(fmaf(-2.0f, lg[r], vsum));
    }
    if (lr == 15) {
#pragma unroll
      for (int r = 0; r < 4; ++r)
        logits[w][lh * 4 + r] = lg[r] + vbias;   // wave-private: no barrier
    }

    // ---- per-wave online softmax with defer-max (T13) ----
    float lv = logits[w][lr];         // same-wave LDS RAW: lgkmcnt only
    float mx = lv;
#pragma unroll
    for (int k = 1; k <= 8; k <<= 1) mx = fmaxf(mx, __shfl_xor(mx, k, 64));
    if (mx > m_run + DEFER_THR) {     // wave-uniform branch; rare after tile 0
      const float e_old = __expf(m_run - mx);
      s_run *= e_old;
#pragma unroll
      for (int kt = 0; kt < 4; ++kt)
#pragma unroll
        for (int j = 0; j < 8; ++j) rc[kt][j] *= e_old;
      m_run = mx;
    }
    const float pr = __expf(lv - m_run);        // bounded by e^DEFER_THR
    float ss = pr;
#pragma unroll
    for (int k = 1; k <= 8; k <<= 1) ss += __shfl_xor(ss, k, 64);
    s_run += ss;

    // ---- per-lane context accumulate: bf2f + fmac only ----
#pragma unroll
    for (int kt = 0; kt < 4; ++kt) {
#pragma unroll
      for (int j = 0; j < 8; ++j) {
        rc[kt][j] = fmaf(pr, bf2f((unsigned short)afrag[kt][j]), rc[kt][j]);
      }
    }

    // ---- scheduling fence only (no block sync): cvt may not hoist up ----
    __builtin_amdgcn_sched_barrier(0);
    if (it + 1 < TILES_PER_BLK) cvt_tile(pf, afrag);
  }

  // ---- one-time 16-row reduce + cross-wave merge ----
  if (l == 0) { fm[w] = m_run; fs[w] = s_run; }
  __syncthreads();
  const float m_blk = fmaxf(fmaxf(fm[0], fm[1]), fmaxf(fm[2], fm[3]));
  const float e_w   = __expf(m_run - m_blk);
#pragma unroll
  for (int kt = 0; kt < 4; ++kt) {
    float cs[8];
#pragma unroll
    for (int j = 0; j < 8; ++j) cs[j] = row_reduce16(rc[kt][j]);
    if (lr == 15) {
      f32x4 v0 = {cs[0] * e_w, cs[1] * e_w, cs[2] * e_w, cs[3] * e_w};
      f32x4 v1 = {cs[4] * e_w, cs[5] * e_w, cs[6] * e_w, cs[7] * e_w};
      *(f32x4*)&fin[w][kt * 32 + lh * 8]     = v0;
      *(f32x4*)&fin[w][kt * 32 + lh * 8 + 4] = v1;
    }
  }
  __syncthreads();

  float* pb = pbuf + (size_t)bidx * P_STRIDE;
  if (tid < 128) {
    pb[tid] = fin[0][tid] + fin[1][tid] + fin[2][tid] + fin[3][tid];
  } else if (tid == 128) {
    pb[128] = m_blk;
  } else if (tid == 129) {
    float sb = fs[0] * __expf(fm[0] - m_blk) + fs[1] * __expf(fm[1] - m_blk)
             + fs[2] * __expf(fm[2] - m_blk) + fs[3] * __expf(fm[3] - m_blk);
    pb[129] = sb;
  }
}

// ---------------------------------------------------------------------------
// Kernel 2: combine 16 block-partials per batch with global softmax rescale
// ---------------------------------------------------------------------------
__global__ __launch_bounds__(128) void k_combine(const float* __restrict__ pbuf,
                                                 float* __restrict__ out)
{
  const int b = blockIdx.x, tid = threadIdx.x;
  __shared__ float sm[16], sden[16];
  const float* base = pbuf + (size_t)b * 16 * P_STRIDE;

  if (tid < 16) {
    sm[tid]   = base[tid * P_STRIDE + 128];
    sden[tid] = base[tid * P_STRIDE + 129];
  }
  __syncthreads();

  float mx = -3.0e38f;
#pragma unroll
  for (int i = 0; i < 16; ++i) mx = fmaxf(mx, sm[i]);
  float den = 0.0f, c = 0.0f;
#pragma unroll
  for (int i = 0; i < 16; ++i) {
    float e = __expf(sm[i] - mx);
    den += sden[i] * e;
    c = fmaf(base[(size_t)i * P_STRIDE + tid], e, c);
  }
  out[b * D_SZ + tid] = c / den;
}

// ---------------------------------------------------------------------------
extern "C" void kernel_launch(void* const* d_in, const int* in_sizes, int n_in,
                              void* d_out, int out_size, void* d_ws, size_t ws_size,
                              hipStream_t stream) {
  const float* x  = (const float*)d_in[0];  // [B,T,D]
  const float* wk = (const float*)d_in[1];  // [D,U]
  const float* wb = (const float*)d_in[2];  // [U]
  const float* vk = (const float*)d_in[3];  // [U,1]
  const float* vb = (const float*)d_in[4];  // [1]
  float* out = (float*)d_out;               // [B,D]

  unsigned short* wt = (unsigned short*)d_ws;       // 32 KB bf16 Wt[u][d] (prescaled)
  float* pbuf = (float*)((char*)d_ws + 32768);      // 1024 * 132 floats

  k_prep<<<64, 256, 0, stream>>>(wk, wt);
  k_partial<<<GRID_P, 256, 0, stream>>>(x, wt, wb, vk, vb, pbuf);
  k_combine<<<B_SZ, 128, 0, stream>>>(pbuf, out);
}

// Round 14
// 57.902 us; speedup vs baseline: 1.5596x; 1.0616x over previous
//
#include <hip/hip_runtime.h>
#include <hip/hip_bf16.h>

typedef __attribute__((ext_vector_type(8))) short short8;
typedef __attribute__((ext_vector_type(4))) float f32x4;
typedef __attribute__((ext_vector_type(4))) int int4v;

#define B_SZ 64
#define T_SZ 8192
#define D_SZ 128
#define U_SZ 128
#define T_TILE 64
#define GRID_P 512
#define TILES_PER_BLK 16          /* 512 blocks x 16 tiles x 64 rows = 64*8192 */
#define BLKS_PER_B 8              /* GRID_P / B_SZ */
#define P_STRIDE 132              /* c[128] + m + s, padded */
#define WT_LD 136                 /* bf16 row stride: 272B */
#define TANH_SCALE 2.8853900817779268f   /* 2*log2(e): folds tanh's 2x and exp's log2e */
#define DEFER_THR 8.0f            /* defer-max rescale threshold (T13) */

__device__ __forceinline__ unsigned short f2bf(float f) {
  unsigned int u = __builtin_bit_cast(unsigned int, f);
  u += 0x7fffu + ((u >> 16) & 1u);
  return (unsigned short)(u >> 16);
}

__device__ __forceinline__ float bf2f(unsigned short s) {
  return __builtin_bit_cast(float, (unsigned int)s << 16);
}

__device__ __forceinline__ float exp2_fast(float xs) {
  float e;
  asm("v_exp_f32 %0, %1" : "=v"(e) : "v"(xs));   // 2^xs
  return e;
}

// DPP row-reduce within each 16-lane row (VALU pipe only).
template<int CTRL>
__device__ __forceinline__ float dpp_add(float v) {
  int t = __builtin_amdgcn_update_dpp(0, __builtin_bit_cast(int, v),
                                      CTRL, 0xf, 0xf, true);
  return v + __builtin_bit_cast(float, t);
}
__device__ __forceinline__ float row_reduce16(float v) {
  v = dpp_add<0x118>(v);  // row_shr:8
  v = dpp_add<0x114>(v);  // row_shr:4
  v = dpp_add<0x112>(v);  // row_shr:2
  v = dpp_add<0x111>(v);  // row_shr:1
  return v;               // lane lr==15 of each 16-lane row holds the sum
}

// fp32x8 -> bf16x8 via hardware packed converts (RNE)
__device__ __forceinline__ void cvt_tile(const f32x4 pf[8], short8 afrag[4]) {
#pragma unroll
  for (int kt = 0; kt < 4; ++kt) {
    f32x4 f0 = pf[kt * 2], f1 = pf[kt * 2 + 1];
    int w0, w1, w2, w3;
    asm("v_cvt_pk_bf16_f32 %0, %1, %2" : "=v"(w0) : "v"(f0[0]), "v"(f0[1]));
    asm("v_cvt_pk_bf16_f32 %0, %1, %2" : "=v"(w1) : "v"(f0[2]), "v"(f0[3]));
    asm("v_cvt_pk_bf16_f32 %0, %1, %2" : "=v"(w2) : "v"(f1[0]), "v"(f1[1]));
    asm("v_cvt_pk_bf16_f32 %0, %1, %2" : "=v"(w3) : "v"(f1[2]), "v"(f1[3]));
    int4v w = {w0, w1, w2, w3};
    afrag[kt] = __builtin_bit_cast(short8, w);
  }
}

// ---------------------------------------------------------------------------
// Kernel 0: W [d][u] fp32 -> Wt [u][d] bf16 PRESCALED by 2*log2e (once, tiny)
// ---------------------------------------------------------------------------
__global__ void k_prep(const float* __restrict__ wk, unsigned short* __restrict__ wt) {
  int i = blockIdx.x * 256 + threadIdx.x;
  if (i < D_SZ * U_SZ) {
    int d = i >> 7, u = i & 127;
    wt[u * D_SZ + d] = f2bf(wk[i] * TANH_SCALE);
  }
}

// ---------------------------------------------------------------------------
// Kernel 1: R12 body EXACTLY; single change = stream shape. 512 blocks x
// 16 tiles (was 1024 x 8): halves the concurrent HBM read-stream count and
// doubles per-stream run length (512 KB sequential per block) for DRAM
// row-buffer locality. CU arithmetic (11.2 B/cyc/CU fair share): memory
// 11.7K cyc/round >> LDS 4-6K, VALU 3.2K -> memory-paced; the 52-vs-39 us
// gap is stream efficiency, not a compute pipe (R12's VALU cut was neutral).
// ---------------------------------------------------------------------------
__global__ __launch_bounds__(256) void k_partial(
    const float* __restrict__ x, const unsigned short* __restrict__ wt_g,
    const float* __restrict__ wb, const float* __restrict__ v,
    const float* __restrict__ vb, float* __restrict__ pbuf)
{
  __shared__ unsigned short wt[U_SZ][WT_LD];  // 34816 B
  __shared__ float wb_s[U_SZ], v_s[U_SZ];     // 1 KB
  __shared__ float logits[4][16];             // wave-private slices
  __shared__ float fin[4][D_SZ];              // final merge buffers
  __shared__ float fm[4], fs[4];

  const int tid  = threadIdx.x;
  const int bidx = blockIdx.x;

  for (int i = tid; i < U_SZ * 16; i += 256) {
    int row = i >> 4, c16 = i & 15;
    uint4 val = ((const uint4*)wt_g)[i];
    *(uint4*)&wt[row][c16 * 8] = val;
  }
  if (tid < U_SZ) { wb_s[tid] = wb[tid] * TANH_SCALE; v_s[tid] = v[tid]; }
  __syncthreads();

  const int w  = tid >> 6;          // wave 0..3 -> rows w*16..w*16+15 of tile
  const int l  = tid & 63;
  const int lr = l & 15;            // A row within the wave's 16-row subtile
  const int lh = l >> 4;            // k-subchunk / D-col group
  const float vbias = vb[0];

  // loop-invariant: sum of v over this lane's u-column set
  float vsum = 0.0f;
#pragma unroll
  for (int ut = 0; ut < 8; ++ut) vsum += v_s[ut * 16 + lr];

  const int b        = bidx >> 3;                          // /BLKS_PER_B
  const int row0     = (bidx & (BLKS_PER_B - 1)) * (TILES_PER_BLK * T_TILE);
  const float* xbase = x + ((size_t)b * T_SZ + row0 + w * 16 + lr) * D_SZ + lh * 8;

  f32x4 pf[8];
#pragma unroll
  for (int kt = 0; kt < 4; ++kt) {
    pf[kt * 2]     = *(const f32x4*)(xbase + kt * 32);
    pf[kt * 2 + 1] = *(const f32x4*)(xbase + kt * 32 + 4);
  }
  short8 afrag[4];
  cvt_tile(pf, afrag);

  float m_run = -3.0e38f, s_run = 0.0f;
  float rc[4][8];
#pragma unroll
  for (int kt = 0; kt < 4; ++kt)
#pragma unroll
    for (int j = 0; j < 8; ++j) rc[kt][j] = 0.0f;

  for (int it = 0; it < TILES_PER_BLK; ++it) {
    // issue next tile's loads; pinned at the top by sched_barrier below
    if (it + 1 < TILES_PER_BLK) {
      const float* p = xbase + (size_t)(it + 1) * T_TILE * D_SZ;
#pragma unroll
      for (int kt = 0; kt < 4; ++kt) {
        pf[kt * 2]     = *(const f32x4*)(p + kt * 32);
        pf[kt * 2 + 1] = *(const f32x4*)(p + kt * 32 + 4);
      }
      __builtin_amdgcn_sched_barrier(0);  // loads may not sink below this
    }

    // ---- logits: 8 u-tiles x 4 k-tiles MFMA; bias in acc init;
    //      lg accumulates sum(v*rcp(2^acc + 1)) ----
    float lg[4] = {0.f, 0.f, 0.f, 0.f};
#pragma unroll
    for (int ut = 0; ut < 8; ++ut) {
      const float wbv = wb_s[ut * 16 + lr];
      f32x4 acc = {wbv, wbv, wbv, wbv};
#pragma unroll
      for (int kt = 0; kt < 4; ++kt) {
        short8 bfrag = *(const short8*)&wt[ut * 16 + lr][kt * 32 + lh * 8];
        acc = __builtin_amdgcn_mfma_f32_16x16x32_bf16(afrag[kt], bfrag, acc, 0, 0, 0);
      }
      const float vv = v_s[ut * 16 + lr];
#pragma unroll
      for (int r = 0; r < 4; ++r)
        lg[r] = fmaf(vv, __builtin_amdgcn_rcpf(exp2_fast(acc[r]) + 1.0f), lg[r]);
    }
#pragma unroll
    for (int r = 0; r < 4; ++r) {
      lg[r] = row_reduce16(fmaf(-2.0f, lg[r], vsum));
    }
    if (lr == 15) {
#pragma unroll
      for (int r = 0; r < 4; ++r)
        logits[w][lh * 4 + r] = lg[r] + vbias;   // wave-private: no barrier
    }

    // ---- per-wave online softmax with defer-max (T13) ----
    float lv = logits[w][lr];         // same-wave LDS RAW: lgkmcnt only
    float mx = lv;
#pragma unroll
    for (int k = 1; k <= 8; k <<= 1) mx = fmaxf(mx, __shfl_xor(mx, k, 64));
    if (mx > m_run + DEFER_THR) {     // wave-uniform branch; rare after tile 0
      const float e_old = __expf(m_run - mx);
      s_run *= e_old;
#pragma unroll
      for (int kt = 0; kt < 4; ++kt)
#pragma unroll
        for (int j = 0; j < 8; ++j) rc[kt][j] *= e_old;
      m_run = mx;
    }
    const float pr = __expf(lv - m_run);        // bounded by e^DEFER_THR
    float ss = pr;
#pragma unroll
    for (int k = 1; k <= 8; k <<= 1) ss += __shfl_xor(ss, k, 64);
    s_run += ss;

    // ---- per-lane context accumulate: bf2f + fmac only ----
#pragma unroll
    for (int kt = 0; kt < 4; ++kt) {
#pragma unroll
      for (int j = 0; j < 8; ++j) {
        rc[kt][j] = fmaf(pr, bf2f((unsigned short)afrag[kt][j]), rc[kt][j]);
      }
    }

    // ---- scheduling fence only (no block sync): cvt may not hoist up ----
    __builtin_amdgcn_sched_barrier(0);
    if (it + 1 < TILES_PER_BLK) cvt_tile(pf, afrag);
  }

  // ---- one-time 16-row reduce + cross-wave merge ----
  if (l == 0) { fm[w] = m_run; fs[w] = s_run; }
  __syncthreads();
  const float m_blk = fmaxf(fmaxf(fm[0], fm[1]), fmaxf(fm[2], fm[3]));
  const float e_w   = __expf(m_run - m_blk);
#pragma unroll
  for (int kt = 0; kt < 4; ++kt) {
    float cs[8];
#pragma unroll
    for (int j = 0; j < 8; ++j) cs[j] = row_reduce16(rc[kt][j]);
    if (lr == 15) {
      f32x4 v0 = {cs[0] * e_w, cs[1] * e_w, cs[2] * e_w, cs[3] * e_w};
      f32x4 v1 = {cs[4] * e_w, cs[5] * e_w, cs[6] * e_w, cs[7] * e_w};
      *(f32x4*)&fin[w][kt * 32 + lh * 8]     = v0;
      *(f32x4*)&fin[w][kt * 32 + lh * 8 + 4] = v1;
    }
  }
  __syncthreads();

  float* pb = pbuf + (size_t)bidx * P_STRIDE;
  if (tid < 128) {
    pb[tid] = fin[0][tid] + fin[1][tid] + fin[2][tid] + fin[3][tid];
  } else if (tid == 128) {
    pb[128] = m_blk;
  } else if (tid == 129) {
    float sb = fs[0] * __expf(fm[0] - m_blk) + fs[1] * __expf(fm[1] - m_blk)
             + fs[2] * __expf(fm[2] - m_blk) + fs[3] * __expf(fm[3] - m_blk);
    pb[129] = sb;
  }
}

// ---------------------------------------------------------------------------
// Kernel 2: combine 8 block-partials per batch with global softmax rescale
// ---------------------------------------------------------------------------
__global__ __launch_bounds__(128) void k_combine(const float* __restrict__ pbuf,
                                                 float* __restrict__ out)
{
  const int b = blockIdx.x, tid = threadIdx.x;
  __shared__ float sm[BLKS_PER_B], sden[BLKS_PER_B];
  const float* base = pbuf + (size_t)b * BLKS_PER_B * P_STRIDE;

  if (tid < BLKS_PER_B) {
    sm[tid]   = base[tid * P_STRIDE + 128];
    sden[tid] = base[tid * P_STRIDE + 129];
  }
  __syncthreads();

  float mx = -3.0e38f;
#pragma unroll
  for (int i = 0; i < BLKS_PER_B; ++i) mx = fmaxf(mx, sm[i]);
  float den = 0.0f, c = 0.0f;
#pragma unroll
  for (int i = 0; i < BLKS_PER_B; ++i) {
    float e = __expf(sm[i] - mx);
    den += sden[i] * e;
    c = fmaf(base[(size_t)i * P_STRIDE + tid], e, c);
  }
  out[b * D_SZ + tid] = c / den;
}

// ---------------------------------------------------------------------------
extern "C" void kernel_launch(void* const* d_in, const int* in_sizes, int n_in,
                              void* d_out, int out_size, void* d_ws, size_t ws_size,
                              hipStream_t stream) {
  const float* x  = (const float*)d_in[0];  // [B,T,D]
  const float* wk = (const float*)d_in[1];  // [D,U]
  const float* wb = (const float*)d_in[2];  // [U]
  const float* vk = (const float*)d_in[3];  // [U,1]
  const float* vb = (const float*)d_in[4];  // [1]
  float* out = (float*)d_out;               // [B,D]

  unsigned short* wt = (unsigned short*)d_ws;       // 32 KB bf16 Wt[u][d] (prescaled)
  float* pbuf = (float*)((char*)d_ws + 32768);      // 512 * 132 floats

  k_prep<<<64, 256, 0, stream>>>(wk, wt);
  k_partial<<<GRID_P, 256, 0, stream>>>(x, wt, wb, vk, vb, pbuf);
  k_combine<<<B_SZ, 128, 0, stream>>>(pbuf, out);
}